// Round 17
// baseline (3367.555 us; speedup 1.0000x reference)
//
#include <hip/hip_runtime.h>
#include <cstdint>
#include <cstddef>

#define S_LEN 2048
#define BATCH 64
#define ISZ   256
#define HSZ   128

typedef __attribute__((ext_vector_type(8))) short short8;   // 8 bf16 = 4 VGPR
typedef __attribute__((ext_vector_type(4))) float f32x4;    // MFMA acc

__device__ __forceinline__ uint32_t bfh(float x)   // fp32 -> bf16 bits (RNE)
{
    uint32_t u = __float_as_uint(x);
    u += 0x7fffu + ((u >> 16) & 1u);
    return u >> 16;
}
__device__ __forceinline__ unsigned short f2bf(float x) { return (unsigned short)bfh(x); }
__device__ __forceinline__ uint32_t pk2(float lo, float hi)
{
    return (uint32_t)f2bf(lo) | ((uint32_t)f2bf(hi) << 16);
}
// unpack (exact): elem 2i = p<<16, elem 2i+1 = p & 0xffff0000
__device__ __forceinline__ float ulo(uint32_t p) { return __uint_as_float(p << 16); }
__device__ __forceinline__ float uhi(uint32_t p) { return __uint_as_float(p & 0xffff0000u); }

// ---------------------------------------------------------------------------
// Split-precision bf16 MFMA GEMM (r10, validated): C = A @ W^T (+bias)
// ---------------------------------------------------------------------------
__device__ __forceinline__ void stage_tile(const float* __restrict__ src, int row0,
                                           int K, int k0, int tid,
                                           short* __restrict__ hi, short* __restrict__ lo)
{
    #pragma unroll
    for (int it = 0; it < 4; ++it) {
        const int g   = tid + it * 256;
        const int row = g >> 3;
        const int kg  = (g & 7) * 8;
        const float* p = src + (size_t)(row0 + row) * K + k0 + kg;
        const float4 v0 = *reinterpret_cast<const float4*>(p);
        const float4 v1 = *reinterpret_cast<const float4*>(p + 4);
        const float f[8] = {v0.x, v0.y, v0.z, v0.w, v1.x, v1.y, v1.z, v1.w};
        uint32_t hp[4], lp[4];
        #pragma unroll
        for (int i = 0; i < 4; ++i) {
            const uint32_t h0 = bfh(f[2*i]), h1 = bfh(f[2*i+1]);
            const float r0 = f[2*i]   - __uint_as_float(h0 << 16);
            const float r1 = f[2*i+1] - __uint_as_float(h1 << 16);
            hp[i] = h0 | (h1 << 16);
            lp[i] = bfh(r0) | (bfh(r1) << 16);
        }
        *reinterpret_cast<uint4*>(&hi[row*72 + kg]) = make_uint4(hp[0], hp[1], hp[2], hp[3]);
        *reinterpret_cast<uint4*>(&lo[row*72 + kg]) = make_uint4(lp[0], lp[1], lp[2], lp[3]);
    }
}

template<int LAYOUT>
__global__ __launch_bounds__(256, 2)
void gemm_mfma(const float* __restrict__ A, const float* __restrict__ W,
               const float* __restrict__ bias, float* __restrict__ C,
               int M, int N, int K)
{
    __shared__ short As_hi[128*72];
    __shared__ short As_lo[128*72];
    __shared__ short Ws_hi[128*72];
    __shared__ short Ws_lo[128*72];

    const int tid = threadIdx.x;
    const int wv  = tid >> 6;
    const int l   = tid & 63;
    const int fr  = l & 15;
    const int fk  = (l >> 4) * 8;
    const int m0  = blockIdx.y * 128;
    const int n0  = blockIdx.x * 128;

    f32x4 acc[2][8] = {};

    for (int k0 = 0; k0 < K; k0 += 64) {
        stage_tile(A, m0, K, k0, tid, As_hi, As_lo);
        stage_tile(W, n0, K, k0, tid, Ws_hi, Ws_lo);
        __syncthreads();

        #pragma unroll
        for (int ks = 0; ks < 64; ks += 32) {
            short8 ah[2], al[2], bh[8], bl[8];
            #pragma unroll
            for (int mt = 0; mt < 2; ++mt) {
                const int r = (wv*32 + mt*16 + fr) * 72 + ks + fk;
                ah[mt] = *reinterpret_cast<const short8*>(&As_hi[r]);
                al[mt] = *reinterpret_cast<const short8*>(&As_lo[r]);
            }
            #pragma unroll
            for (int nt = 0; nt < 8; ++nt) {
                const int r = (nt*16 + fr) * 72 + ks + fk;
                bh[nt] = *reinterpret_cast<const short8*>(&Ws_hi[r]);
                bl[nt] = *reinterpret_cast<const short8*>(&Ws_lo[r]);
            }
            #pragma unroll
            for (int mt = 0; mt < 2; ++mt) {
                #pragma unroll
                for (int nt = 0; nt < 8; ++nt) {
                    acc[mt][nt] = __builtin_amdgcn_mfma_f32_16x16x32_bf16(
                        ah[mt], bh[nt], acc[mt][nt], 0, 0, 0);
                    acc[mt][nt] = __builtin_amdgcn_mfma_f32_16x16x32_bf16(
                        ah[mt], bl[nt], acc[mt][nt], 0, 0, 0);
                    acc[mt][nt] = __builtin_amdgcn_mfma_f32_16x16x32_bf16(
                        al[mt], bh[nt], acc[mt][nt], 0, 0, 0);
                }
            }
        }
        __syncthreads();
    }

    const int orow = (l >> 4) * 4;
    #pragma unroll
    for (int nt = 0; nt < 8; ++nt) {
        const int n = n0 + nt*16 + fr;
        const float bv = bias ? bias[n] : 0.f;
        #pragma unroll
        for (int mt = 0; mt < 2; ++mt) {
            const int mbase = m0 + wv*32 + mt*16 + orow;
            const f32x4 a = acc[mt][nt];
            if (LAYOUT == 0) {
                #pragma unroll
                for (int r = 0; r < 4; ++r)
                    C[(size_t)(mbase + r) * N + n] = a[r] + bv;
            } else {
                float4 o;
                o.x = a[0] + bv; o.y = a[1] + bv; o.z = a[2] + bv; o.w = a[3] + bv;
                *reinterpret_cast<float4*>(
                    &C[(size_t)(mbase >> 6) * ((size_t)N * 64) +
                       (size_t)n * 64 + (mbase & 63)]) = o;
            }
        }
    }
}

// ---------------------------------------------------------------------------
// K3/K4 fusion precompute:  Wc = comb_w @ attn_w, bc = comb_w @ attn_b
// logits = (outs@attn_w^T + attn_b)@comb_w^T  ==  outs@Wc^T + bc
// ---------------------------------------------------------------------------
__global__ __launch_bounds__(256)
void fuse_wc(const float* __restrict__ comb_w, const float* __restrict__ attn_w,
             const float* __restrict__ attn_b,
             float* __restrict__ Wc, float* __restrict__ bc)
{
    const int n = blockIdx.x;
    const int k = threadIdx.x;
    if (n < 256) {
        float acc = 0.f;
        for (int p = 0; p < 256; ++p)
            acc = fmaf(comb_w[n*256 + p], attn_w[p*256 + k], acc);
        Wc[n*256 + k] = acc;
    } else {
        float acc = 0.f;
        for (int p = 0; p < 256; ++p)
            acc = fmaf(comb_w[k*256 + p], attn_b[p], acc);
        bc[k] = acc;
    }
}

// ---------------------------------------------------------------------------
// GRU recurrence (r17: ALL weights in LDS, zero VGPR arrays, zero scratch).
// One WG per (direction,batch), 256 threads = 4 waves; r11 partition:
//   thread j <128 (waves 0-1): r-row j + n-row 256+j k[0:64)
//   thread 128+j  (waves 2-3): z-row 128+j + n-row 256+j k[64:128)
// r3-r16 allocator ledger: no >=64-word loop-carried VGPR array ever stays
// resident (8 failed probes).  LDS is the storage class that works:
// per-thread blob of 96 packed-bf16 words, padded to 100 (400B).  Stride
// 100 words == 4 banks (mod 32) -> a wave's b128 read at common offset
// puts lane j in bank-quad (j+c)%8 -> 8 lanes/quad = full 128B/cy LDS
// width, conflict-free (same arithmetic as r9's pad-132, measured 0
// conflicts).  24 independent ds_read_b128/thread/step pipeline under the
// FMA stream.  h stays fp32 (wave-uniform readlane); n-halves combine via
// LDS; raw s_barrier + lgkmcnt(0) keeps x(t+1) prefetch in flight.
// ---------------------------------------------------------------------------
#define RL(v, l) __int_as_float(__builtin_amdgcn_readlane(__float_as_int(v), (l)))

__global__ __launch_bounds__(256, 1)
void gru_scan(const float* __restrict__ xg_f, const float* __restrict__ xg_b,
              const float* __restrict__ whh_f, const float* __restrict__ whh_b,
              const float* __restrict__ bhh_f, const float* __restrict__ bhh_b,
              const float* __restrict__ h0,     // (2,64,128)
              float* __restrict__ outs,         // (S,64,256)
              float* __restrict__ hid_out)      // (2,64,128)
{
    const int j    = threadIdx.x;        // 0..255
    const int lane = j & 63;
    const int dir  = blockIdx.x >> 6;
    const int b    = blockIdx.x & 63;
    const bool low = (j < 128);          // waves 0,1 (wave-uniform)
    const int jj   = j & 127;

    const float* xg  = dir ? xg_b  : xg_f;
    const float* whh = dir ? whh_b : whh_f;
    const float* bhh = dir ? bhh_b : bhh_f;

    __shared__ uint32_t wlds[256 * 100];   // 100 KB weight blobs
    __shared__ float hs[128];
    __shared__ float gz[128];    // z-gate dot (from high threads)
    __shared__ float gnh[128];   // n-gate high-half partial

    uint32_t* blob = &wlds[j * 100];

    // stage main row j: 64 packed words (16 x b128 writes, conflict-free)
    #pragma unroll
    for (int g = 0; g < 16; ++g) {
        const float4 v0 = *reinterpret_cast<const float4*>(&whh[(size_t)j*128 + g*8]);
        const float4 v1 = *reinterpret_cast<const float4*>(&whh[(size_t)j*128 + g*8 + 4]);
        uint4 p;
        p.x = pk2(v0.x, v0.y); p.y = pk2(v0.z, v0.w);
        p.z = pk2(v1.x, v1.y); p.w = pk2(v1.z, v1.w);
        *reinterpret_cast<uint4*>(&blob[g*4]) = p;
    }
    // stage n-row 256+jj, own k-half: 32 packed words
    {
        const size_t nbase = (size_t)(256 + jj) * 128 + (low ? 0 : 64);
        #pragma unroll
        for (int g = 0; g < 8; ++g) {
            const float4 v0 = *reinterpret_cast<const float4*>(&whh[nbase + g*8]);
            const float4 v1 = *reinterpret_cast<const float4*>(&whh[nbase + g*8 + 4]);
            uint4 p;
            p.x = pk2(v0.x, v0.y); p.y = pk2(v0.z, v0.w);
            p.z = pk2(v1.x, v1.y); p.w = pk2(v1.z, v1.w);
            *reinterpret_cast<uint4*>(&blob[64 + g*4]) = p;
        }
    }

    const float bh  = bhh[j];
    const float bhn = low ? bhh[256 + jj] : 0.f;

    float hj = 0.f, xr = 0.f, xz = 0.f, xn = 0.f;
    if (low) {
        hj = h0[dir * (64*128) + b * 128 + j];
        hs[j] = hj;
        const int s0 = dir ? (S_LEN - 1) : 0;
        const float* xrow = xg + ((size_t)s0 * 64 + b) * 384;
        xr = xrow[j]; xz = xrow[j + 128]; xn = xrow[j + 256];
    }
    __syncthreads();   // staging + hs complete (one-time full drain is fine)

    for (int t = 0; t < S_LEN; ++t) {
        const float hv0 = hs[lane];
        const float hv1 = hs[64 + lane];

        float pxr = 0.f, pxz = 0.f, pxn = 0.f;
        if (low && t + 1 < S_LEN) {
            const int s1 = dir ? (S_LEN - 2 - t) : (t + 1);
            const float* xrow = xg + ((size_t)s1 * 64 + b) * 384;
            pxr = xrow[j]; pxz = xrow[j + 128]; pxn = xrow[j + 256];
        }

        float a0 = 0.f, a1 = 0.f, a2 = 0.f, a3 = 0.f;  // main row
        float q0 = 0.f, q1 = 0.f;                      // n-row half
        if (low) {
            #pragma unroll
            for (int g = 0; g < 8; ++g) {              // k in [0,64): main + n
                const uint4 mw = *reinterpret_cast<const uint4*>(&blob[g*4]);
                const uint4 nw = *reinterpret_cast<const uint4*>(&blob[64 + g*4]);
                const int kb = g * 8;
                const float s0 = RL(hv0, kb+0), s1 = RL(hv0, kb+1);
                const float s2 = RL(hv0, kb+2), s3 = RL(hv0, kb+3);
                const float s4 = RL(hv0, kb+4), s5 = RL(hv0, kb+5);
                const float s6 = RL(hv0, kb+6), s7 = RL(hv0, kb+7);
                a0 = fmaf(ulo(mw.x), s0, a0);  q0 = fmaf(ulo(nw.x), s0, q0);
                a1 = fmaf(uhi(mw.x), s1, a1);  q1 = fmaf(uhi(nw.x), s1, q1);
                a2 = fmaf(ulo(mw.y), s2, a2);  q0 = fmaf(ulo(nw.y), s2, q0);
                a3 = fmaf(uhi(mw.y), s3, a3);  q1 = fmaf(uhi(nw.y), s3, q1);
                a0 = fmaf(ulo(mw.z), s4, a0);  q0 = fmaf(ulo(nw.z), s4, q0);
                a1 = fmaf(uhi(mw.z), s5, a1);  q1 = fmaf(uhi(nw.z), s5, q1);
                a2 = fmaf(ulo(mw.w), s6, a2);  q0 = fmaf(ulo(nw.w), s6, q0);
                a3 = fmaf(uhi(mw.w), s7, a3);  q1 = fmaf(uhi(nw.w), s7, q1);
            }
            #pragma unroll
            for (int g = 8; g < 16; ++g) {             // k in [64,128): main only
                const uint4 mw = *reinterpret_cast<const uint4*>(&blob[g*4]);
                const int kb = (g - 8) * 8;
                a0 = fmaf(ulo(mw.x), RL(hv1, kb+0), a0);
                a1 = fmaf(uhi(mw.x), RL(hv1, kb+1), a1);
                a2 = fmaf(ulo(mw.y), RL(hv1, kb+2), a2);
                a3 = fmaf(uhi(mw.y), RL(hv1, kb+3), a3);
                a0 = fmaf(ulo(mw.z), RL(hv1, kb+4), a0);
                a1 = fmaf(uhi(mw.z), RL(hv1, kb+5), a1);
                a2 = fmaf(ulo(mw.w), RL(hv1, kb+6), a2);
                a3 = fmaf(uhi(mw.w), RL(hv1, kb+7), a3);
            }
        } else {
            #pragma unroll
            for (int g = 0; g < 8; ++g) {              // k in [0,64): main only
                const uint4 mw = *reinterpret_cast<const uint4*>(&blob[g*4]);
                const int kb = g * 8;
                a0 = fmaf(ulo(mw.x), RL(hv0, kb+0), a0);
                a1 = fmaf(uhi(mw.x), RL(hv0, kb+1), a1);
                a2 = fmaf(ulo(mw.y), RL(hv0, kb+2), a2);
                a3 = fmaf(uhi(mw.y), RL(hv0, kb+3), a3);
                a0 = fmaf(ulo(mw.z), RL(hv0, kb+4), a0);
                a1 = fmaf(uhi(mw.z), RL(hv0, kb+5), a1);
                a2 = fmaf(ulo(mw.w), RL(hv0, kb+6), a2);
                a3 = fmaf(uhi(mw.w), RL(hv0, kb+7), a3);
            }
            #pragma unroll
            for (int g = 8; g < 16; ++g) {             // k in [64,128): main + n
                const uint4 mw = *reinterpret_cast<const uint4*>(&blob[g*4]);
                const uint4 nw = *reinterpret_cast<const uint4*>(&blob[64 + (g-8)*4]);
                const int kb = (g - 8) * 8;
                const float s0 = RL(hv1, kb+0), s1 = RL(hv1, kb+1);
                const float s2 = RL(hv1, kb+2), s3 = RL(hv1, kb+3);
                const float s4 = RL(hv1, kb+4), s5 = RL(hv1, kb+5);
                const float s6 = RL(hv1, kb+6), s7 = RL(hv1, kb+7);
                a0 = fmaf(ulo(mw.x), s0, a0);  q0 = fmaf(ulo(nw.x), s0, q0);
                a1 = fmaf(uhi(mw.x), s1, a1);  q1 = fmaf(uhi(nw.x), s1, q1);
                a2 = fmaf(ulo(mw.y), s2, a2);  q0 = fmaf(ulo(nw.y), s2, q0);
                a3 = fmaf(uhi(mw.y), s3, a3);  q1 = fmaf(uhi(nw.y), s3, q1);
                a0 = fmaf(ulo(mw.z), s4, a0);  q0 = fmaf(ulo(nw.z), s4, q0);
                a1 = fmaf(uhi(mw.z), s5, a1);  q1 = fmaf(uhi(nw.z), s5, q1);
                a2 = fmaf(ulo(mw.w), s6, a2);  q0 = fmaf(ulo(nw.w), s6, q0);
                a3 = fmaf(uhi(mw.w), s7, a3);  q1 = fmaf(uhi(nw.w), s7, q1);
            }
        }
        const float amain = (a0 + a1) + (a2 + a3) + bh;
        const float npart = q0 + q1;
        if (!low) {
            gz[jj]  = amain;
            gnh[jj] = npart;
        }

        asm volatile("s_waitcnt lgkmcnt(0)" ::: "memory");
        __builtin_amdgcn_s_barrier();

        if (low) {
            const float hr = amain;
            const float hz = gz[j];
            const float hn = (npart + bhn) + gnh[j];
            const float r = 1.f / (1.f + __expf(-(xr + hr)));
            const float z = 1.f / (1.f + __expf(-(xz + hz)));
            const float x2 = xn + r * hn;
            const float ax = fabsf(x2);
            const float e  = __expf(-2.f * ax);
            const float nn = copysignf((1.f - e) / (1.f + e), x2);  // tanh
            const float hnew = nn + z * (hj - nn);   // (1-z)*n + z*h
            hj = hnew;
            hs[j] = hnew;
            const int s = dir ? (S_LEN - 1 - t) : t;
            outs[((size_t)s * 64 + b) * 256 + dir * 128 + j] = hnew;
            xr = pxr; xz = pxz; xn = pxn;
        }

        asm volatile("s_waitcnt lgkmcnt(0)" ::: "memory");
        __builtin_amdgcn_s_barrier();
    }

    if (low) hid_out[dir * (64*128) + b * 128 + j] = hj;
}

// ---------------------------------------------------------------------------
// Batch-axis softmax (over b, 64 lanes = one wave) + weighted partial
// reduction over a 32-step s-chunk.  logits are in (S, C, B) layout.
// ---------------------------------------------------------------------------
__global__ __launch_bounds__(256)
void attn_reduce(const float* __restrict__ lt,    // (S,256,64)
                 const float* __restrict__ outs,  // (S,64,256)
                 float* __restrict__ part)        // (64 chunks,64 b,256 c)
{
    __shared__ float ltile[64 * 64];
    __shared__ float otile[64 * 65];

    const int tid  = threadIdx.x;
    const int lane = tid & 63;
    const int wv   = tid >> 6;
    const int c0   = blockIdx.x * 64;
    const int sc   = blockIdx.y;

    float acc[16];
    #pragma unroll
    for (int i = 0; i < 16; ++i) acc[i] = 0.f;

    for (int si = 0; si < 32; ++si) {
        const int s = sc * 32 + si;

        const float4* src = reinterpret_cast<const float4*>(
            lt + (size_t)s * 16384 + (size_t)c0 * 64);
        #pragma unroll
        for (int i = 0; i < 4; ++i)
            reinterpret_cast<float4*>(ltile)[tid + i * 256] = src[tid + i * 256];

        #pragma unroll
        for (int i = 0; i < 4; ++i) {
            int idx = tid + i * 256;
            int bb = idx >> 4, c4 = (idx & 15) * 4;
            float4 v = *reinterpret_cast<const float4*>(
                &outs[((size_t)s * 64 + bb) * 256 + c0 + c4]);
            otile[bb*65 + c4+0] = v.x; otile[bb*65 + c4+1] = v.y;
            otile[bb*65 + c4+2] = v.z; otile[bb*65 + c4+3] = v.w;
        }
        __syncthreads();

        #pragma unroll
        for (int ci = 0; ci < 16; ++ci) {
            int c = wv * 16 + ci;
            float x = ltile[c * 64 + lane];
            float m = x;
            #pragma unroll
            for (int off = 32; off; off >>= 1)
                m = fmaxf(m, __shfl_xor(m, off));
            float e = __expf(x - m);
            float ssum = e;
            #pragma unroll
            for (int off = 32; off; off >>= 1)
                ssum += __shfl_xor(ssum, off);
            float attn = e / ssum;
            acc[ci] += attn * otile[lane * 65 + c];
        }
        __syncthreads();
    }

    #pragma unroll
    for (int ci = 0; ci < 16; ++ci) {
        int c = wv * 16 + ci;
        part[(size_t)sc * 16384 + (size_t)lane * 256 + c0 + c] = acc[ci];
    }
}

__global__ __launch_bounds__(256)
void reduce_part(const float* __restrict__ part, float* __restrict__ sent)
{
    int idx = blockIdx.x * 256 + threadIdx.x;
    float s = 0.f;
    for (int sc = 0; sc < 64; ++sc)
        s += part[(size_t)sc * 16384 + idx];
    sent[idx] = s;
}

// ---------------------------------------------------------------------------
extern "C" void kernel_launch(void* const* d_in, const int* in_sizes, int n_in,
                              void* d_out, int out_size, void* d_ws, size_t ws_size,
                              hipStream_t stream)
{
    const float* inp    = (const float*)d_in[0];
    const float* hid0   = (const float*)d_in[1];
    const float* w_ih_f = (const float*)d_in[2];
    const float* w_hh_f = (const float*)d_in[3];
    const float* b_ih_f = (const float*)d_in[4];
    const float* b_hh_f = (const float*)d_in[5];
    const float* w_ih_b = (const float*)d_in[6];
    const float* w_hh_b = (const float*)d_in[7];
    const float* b_ih_b = (const float*)d_in[8];
    const float* b_hh_b = (const float*)d_in[9];
    const float* attn_w = (const float*)d_in[10];
    const float* attn_b = (const float*)d_in[11];
    const float* comb_w = (const float*)d_in[12];

    float* out = (float*)d_out;   // [0,16384): sent, [16384,32768): hid_out

    char* ws = (char*)d_ws;
    const size_t XG_BYTES = (size_t)S_LEN * BATCH * 384 * 4;  // 201,326,592
    const size_t OS_BYTES = (size_t)S_LEN * BATCH * 256 * 4;  // 134,217,728
    if (ws_size < 2 * XG_BYTES + OS_BYTES) return;

    float* xg_f   = (float*)(ws);
    float* xg_b   = (float*)(ws + XG_BYTES);
    float* outs   = (float*)(ws + 2 * XG_BYTES);
    float* logits = (float*)(ws + XG_BYTES);          // reuse xg_b (dead after gru)
    float* Wc     = (float*)(ws + XG_BYTES + (size_t)160 * 1024 * 1024);  // spare tail
    float* bc     = Wc + 256 * 256;
    float* part   = (float*)(ws);                     // reuse xg_f (dead after gru)

    const int M = S_LEN * BATCH;                // 131072
    dim3 blk(256);

    // K1: input-side gates, both directions (MFMA split-bf16)
    gemm_mfma<0><<<dim3(3, 1024), blk, 0, stream>>>(inp, w_ih_f, b_ih_f, xg_f, M, 384, 256);
    gemm_mfma<0><<<dim3(3, 1024), blk, 0, stream>>>(inp, w_ih_b, b_ih_b, xg_b, M, 384, 256);

    // K2: sequential bidirectional GRU (128 WGs x 256 thr, LDS weights)
    gru_scan<<<dim3(128), dim3(256), 0, stream>>>(
        xg_f, xg_b, w_hh_f, w_hh_b, b_hh_f, b_hh_b, hid0, outs, out + 16384);

    // Kf: Wc = comb_w@attn_w, bc = comb_w@attn_b  (K3/K4 algebraic fusion)
    fuse_wc<<<dim3(257), blk, 0, stream>>>(comb_w, attn_w, attn_b, Wc, bc);

    // K4': logits = outs @ Wc^T + bc, stored transposed (S,C,B) (MFMA)
    gemm_mfma<1><<<dim3(2, 1024), blk, 0, stream>>>(outs, Wc, bc, logits, M, 256, 256);

    // K5: softmax over batch + weighted partial sum over s-chunks
    attn_reduce<<<dim3(4, 64), blk, 0, stream>>>(logits, outs, part);

    // K6: final reduction over s-chunks -> sent
    reduce_part<<<dim3(64), blk, 0, stream>>>(part, out);
}

// Round 18
// 2399.759 us; speedup vs baseline: 1.4033x; 1.4033x over previous
//
#include <hip/hip_runtime.h>
#include <cstdint>
#include <cstddef>

#define S_LEN 2048
#define BATCH 64
#define ISZ   256
#define HSZ   128

typedef __attribute__((ext_vector_type(8))) short short8;   // 8 bf16 = 4 VGPR
typedef __attribute__((ext_vector_type(4))) float f32x4;    // MFMA acc

__device__ __forceinline__ uint32_t bfh(float x)   // fp32 -> bf16 bits (RNE)
{
    uint32_t u = __float_as_uint(x);
    u += 0x7fffu + ((u >> 16) & 1u);
    return u >> 16;
}
__device__ __forceinline__ unsigned short f2bf(float x) { return (unsigned short)bfh(x); }
__device__ __forceinline__ uint32_t pk2(float lo, float hi)
{
    return (uint32_t)f2bf(lo) | ((uint32_t)f2bf(hi) << 16);
}
// unpack (exact): elem 2i = p<<16, elem 2i+1 = p & 0xffff0000
__device__ __forceinline__ float ulo(uint32_t p) { return __uint_as_float(p << 16); }
__device__ __forceinline__ float uhi(uint32_t p) { return __uint_as_float(p & 0xffff0000u); }

// ---------------------------------------------------------------------------
// Split-precision bf16 MFMA GEMM (r10, validated): C = A @ W^T (+bias)
// A = Ah+Al, W = Wh+Wl; C ~= AhWh + AhWl + AlWh (~2^-16 rel).
// BM=BN=128, BK=64; 4 waves, 2x8 16x16x32 frags each.
// LAYOUT 0: C[m*N+n];  LAYOUT 1: C[(m>>6)*N*64 + n*64 + (m&63)]  (s,c,b)
// ---------------------------------------------------------------------------
__device__ __forceinline__ void stage_tile(const float* __restrict__ src, int row0,
                                           int K, int k0, int tid,
                                           short* __restrict__ hi, short* __restrict__ lo)
{
    #pragma unroll
    for (int it = 0; it < 4; ++it) {
        const int g   = tid + it * 256;
        const int row = g >> 3;
        const int kg  = (g & 7) * 8;
        const float* p = src + (size_t)(row0 + row) * K + k0 + kg;
        const float4 v0 = *reinterpret_cast<const float4*>(p);
        const float4 v1 = *reinterpret_cast<const float4*>(p + 4);
        const float f[8] = {v0.x, v0.y, v0.z, v0.w, v1.x, v1.y, v1.z, v1.w};
        uint32_t hp[4], lp[4];
        #pragma unroll
        for (int i = 0; i < 4; ++i) {
            const uint32_t h0 = bfh(f[2*i]), h1 = bfh(f[2*i+1]);
            const float r0 = f[2*i]   - __uint_as_float(h0 << 16);
            const float r1 = f[2*i+1] - __uint_as_float(h1 << 16);
            hp[i] = h0 | (h1 << 16);
            lp[i] = bfh(r0) | (bfh(r1) << 16);
        }
        *reinterpret_cast<uint4*>(&hi[row*72 + kg]) = make_uint4(hp[0], hp[1], hp[2], hp[3]);
        *reinterpret_cast<uint4*>(&lo[row*72 + kg]) = make_uint4(lp[0], lp[1], lp[2], lp[3]);
    }
}

template<int LAYOUT>
__global__ __launch_bounds__(256, 2)
void gemm_mfma(const float* __restrict__ A, const float* __restrict__ W,
               const float* __restrict__ bias, float* __restrict__ C,
               int M, int N, int K)
{
    __shared__ short As_hi[128*72];
    __shared__ short As_lo[128*72];
    __shared__ short Ws_hi[128*72];
    __shared__ short Ws_lo[128*72];

    const int tid = threadIdx.x;
    const int wv  = tid >> 6;
    const int l   = tid & 63;
    const int fr  = l & 15;
    const int fk  = (l >> 4) * 8;
    const int m0  = blockIdx.y * 128;
    const int n0  = blockIdx.x * 128;

    f32x4 acc[2][8] = {};

    for (int k0 = 0; k0 < K; k0 += 64) {
        stage_tile(A, m0, K, k0, tid, As_hi, As_lo);
        stage_tile(W, n0, K, k0, tid, Ws_hi, Ws_lo);
        __syncthreads();

        #pragma unroll
        for (int ks = 0; ks < 64; ks += 32) {
            short8 ah[2], al[2], bh[8], bl[8];
            #pragma unroll
            for (int mt = 0; mt < 2; ++mt) {
                const int r = (wv*32 + mt*16 + fr) * 72 + ks + fk;
                ah[mt] = *reinterpret_cast<const short8*>(&As_hi[r]);
                al[mt] = *reinterpret_cast<const short8*>(&As_lo[r]);
            }
            #pragma unroll
            for (int nt = 0; nt < 8; ++nt) {
                const int r = (nt*16 + fr) * 72 + ks + fk;
                bh[nt] = *reinterpret_cast<const short8*>(&Ws_hi[r]);
                bl[nt] = *reinterpret_cast<const short8*>(&Ws_lo[r]);
            }
            #pragma unroll
            for (int mt = 0; mt < 2; ++mt) {
                #pragma unroll
                for (int nt = 0; nt < 8; ++nt) {
                    acc[mt][nt] = __builtin_amdgcn_mfma_f32_16x16x32_bf16(
                        ah[mt], bh[nt], acc[mt][nt], 0, 0, 0);
                    acc[mt][nt] = __builtin_amdgcn_mfma_f32_16x16x32_bf16(
                        ah[mt], bl[nt], acc[mt][nt], 0, 0, 0);
                    acc[mt][nt] = __builtin_amdgcn_mfma_f32_16x16x32_bf16(
                        al[mt], bh[nt], acc[mt][nt], 0, 0, 0);
                }
            }
        }
        __syncthreads();
    }

    const int orow = (l >> 4) * 4;
    #pragma unroll
    for (int nt = 0; nt < 8; ++nt) {
        const int n = n0 + nt*16 + fr;
        const float bv = bias ? bias[n] : 0.f;
        #pragma unroll
        for (int mt = 0; mt < 2; ++mt) {
            const int mbase = m0 + wv*32 + mt*16 + orow;
            const f32x4 a = acc[mt][nt];
            if (LAYOUT == 0) {
                #pragma unroll
                for (int r = 0; r < 4; ++r)
                    C[(size_t)(mbase + r) * N + n] = a[r] + bv;
            } else {
                float4 o;
                o.x = a[0] + bv; o.y = a[1] + bv; o.z = a[2] + bv; o.w = a[3] + bv;
                *reinterpret_cast<float4*>(
                    &C[(size_t)(mbase >> 6) * ((size_t)N * 64) +
                       (size_t)n * 64 + (mbase & 63)]) = o;
            }
        }
    }
}

// ---------------------------------------------------------------------------
// K3/K4 fusion precompute:  Wc = comb_w @ attn_w, bc = comb_w @ attn_b
// logits = (outs@attn_w^T + attn_b)@comb_w^T  ==  outs@Wc^T + bc
// ---------------------------------------------------------------------------
__global__ __launch_bounds__(256)
void fuse_wc(const float* __restrict__ comb_w, const float* __restrict__ attn_w,
             const float* __restrict__ attn_b,
             float* __restrict__ Wc, float* __restrict__ bc)
{
    const int n = blockIdx.x;
    const int k = threadIdx.x;
    if (n < 256) {
        float acc = 0.f;
        for (int p = 0; p < 256; ++p)
            acc = fmaf(comb_w[n*256 + p], attn_w[p*256 + k], acc);
        Wc[n*256 + k] = acc;
    } else {
        float acc = 0.f;
        for (int p = 0; p < 256; ++p)
            acc = fmaf(comb_w[k*256 + p], attn_b[p], acc);
        bc[k] = acc;
    }
}

// ---------------------------------------------------------------------------
// GRU recurrence (r11 EXACT — best of 10 measured designs: 1670us).
// One WG per (direction,batch), 256 threads = 4 waves.
//   thread j <128 (waves 0-1): r-row j + n-row 256+j k[0:64)
//   thread 128+j  (waves 2-3): z-row 128+j + n-row 256+j k[64:128)
// Weights: packed bf16 (wp[64]+wnp[32]); they SPILL by compiler choice and
// stream from scratch via L1 at ~49B/cyc/CU — measured fastest pipe at
// 1 WG/CU (LDS variant: 2652us, issue/latency-bound; fp32 scratch: 1955us).
// h wave-uniform via v_readlane; n-halves combine via LDS; raw s_barrier +
// lgkmcnt(0) keeps the x(t+1) prefetch in flight across barriers.
// ---------------------------------------------------------------------------
#define RL(v, l) __int_as_float(__builtin_amdgcn_readlane(__float_as_int(v), (l)))

__global__ __launch_bounds__(256, 1)
void gru_scan(const float* __restrict__ xg_f, const float* __restrict__ xg_b,
              const float* __restrict__ whh_f, const float* __restrict__ whh_b,
              const float* __restrict__ bhh_f, const float* __restrict__ bhh_b,
              const float* __restrict__ h0,     // (2,64,128)
              float* __restrict__ outs,         // (S,64,256)
              float* __restrict__ hid_out)      // (2,64,128)
{
    const int j    = threadIdx.x;        // 0..255
    const int lane = j & 63;
    const int dir  = blockIdx.x >> 6;
    const int b    = blockIdx.x & 63;
    const bool low = (j < 128);          // waves 0,1 (wave-uniform)
    const int jj   = j & 127;

    const float* xg  = dir ? xg_b  : xg_f;
    const float* whh = dir ? whh_b : whh_f;
    const float* bhh = dir ? bhh_b : bhh_f;

    // main row j packed bf16: wp[i] = (w[2i+1] : w[2i])
    uint32_t wp[64];
    #pragma unroll
    for (int k4 = 0; k4 < 32; ++k4) {
        float4 v = *reinterpret_cast<const float4*>(&whh[(size_t)j * 128 + k4 * 4]);
        wp[k4*2+0] = pk2(v.x, v.y);
        wp[k4*2+1] = pk2(v.z, v.w);
    }
    // n-row 256+jj, own k-half packed: 32 words
    uint32_t wnp[32];
    {
        const size_t nbase = (size_t)(256 + jj) * 128 + (low ? 0 : 64);
        #pragma unroll
        for (int k4 = 0; k4 < 16; ++k4) {
            float4 v = *reinterpret_cast<const float4*>(&whh[nbase + k4 * 4]);
            wnp[k4*2+0] = pk2(v.x, v.y);
            wnp[k4*2+1] = pk2(v.z, v.w);
        }
    }
    #pragma unroll
    for (int i = 0; i < 64; ++i) asm("" : "+v"(wp[i]));
    #pragma unroll
    for (int i = 0; i < 32; ++i) asm("" : "+v"(wnp[i]));

    const float bh  = bhh[j];
    const float bhn = low ? bhh[256 + jj] : 0.f;

    __shared__ float hs[128];
    __shared__ float gz[128];    // z-gate dot (from high threads)
    __shared__ float gnh[128];   // n-gate high-half partial (from high threads)

    float hj = 0.f, xr = 0.f, xz = 0.f, xn = 0.f;
    if (low) {
        hj = h0[dir * (64*128) + b * 128 + j];
        hs[j] = hj;
        const int s0 = dir ? (S_LEN - 1) : 0;
        const float* xrow = xg + ((size_t)s0 * 64 + b) * 384;
        xr = xrow[j]; xz = xrow[j + 128]; xn = xrow[j + 256];
    }
    asm volatile("s_waitcnt lgkmcnt(0)" ::: "memory");
    __builtin_amdgcn_s_barrier();

    for (int t = 0; t < S_LEN; ++t) {
        const float hv0 = hs[lane];
        const float hv1 = hs[64 + lane];

        float pxr = 0.f, pxz = 0.f, pxn = 0.f;
        if (low && t + 1 < S_LEN) {
            const int s1 = dir ? (S_LEN - 2 - t) : (t + 1);
            const float* xrow = xg + ((size_t)s1 * 64 + b) * 384;
            pxr = xrow[j]; pxz = xrow[j + 128]; pxn = xrow[j + 256];
        }

        float a0 = 0.f, a1 = 0.f, a2 = 0.f, a3 = 0.f;  // main row
        float q0 = 0.f, q1 = 0.f;                      // n-row half
        if (low) {
            #pragma unroll
            for (int k = 0; k < 64; k += 4) {
                const uint32_t p0 = wp[k/2],  p1 = wp[k/2+1];
                const uint32_t n0p = wnp[k/2], n1p = wnp[k/2+1];
                const float s0 = RL(hv0, k+0), s1 = RL(hv0, k+1);
                const float s2 = RL(hv0, k+2), s3 = RL(hv0, k+3);
                a0 = fmaf(ulo(p0), s0, a0);  q0 = fmaf(ulo(n0p), s0, q0);
                a1 = fmaf(uhi(p0), s1, a1);  q1 = fmaf(uhi(n0p), s1, q1);
                a2 = fmaf(ulo(p1), s2, a2);  q0 = fmaf(ulo(n1p), s2, q0);
                a3 = fmaf(uhi(p1), s3, a3);  q1 = fmaf(uhi(n1p), s3, q1);
            }
            #pragma unroll
            for (int k = 0; k < 64; k += 4) {
                const uint32_t p0 = wp[32+k/2], p1 = wp[32+k/2+1];
                a0 = fmaf(ulo(p0), RL(hv1, k+0), a0);
                a1 = fmaf(uhi(p0), RL(hv1, k+1), a1);
                a2 = fmaf(ulo(p1), RL(hv1, k+2), a2);
                a3 = fmaf(uhi(p1), RL(hv1, k+3), a3);
            }
        } else {
            #pragma unroll
            for (int k = 0; k < 64; k += 4) {
                const uint32_t p0 = wp[k/2], p1 = wp[k/2+1];
                a0 = fmaf(ulo(p0), RL(hv0, k+0), a0);
                a1 = fmaf(uhi(p0), RL(hv0, k+1), a1);
                a2 = fmaf(ulo(p1), RL(hv0, k+2), a2);
                a3 = fmaf(uhi(p1), RL(hv0, k+3), a3);
            }
            #pragma unroll
            for (int k = 0; k < 64; k += 4) {
                const uint32_t p0 = wp[32+k/2], p1 = wp[32+k/2+1];
                const uint32_t n0p = wnp[k/2],  n1p = wnp[k/2+1];
                const float s0 = RL(hv1, k+0), s1 = RL(hv1, k+1);
                const float s2 = RL(hv1, k+2), s3 = RL(hv1, k+3);
                a0 = fmaf(ulo(p0), s0, a0);  q0 = fmaf(ulo(n0p), s0, q0);
                a1 = fmaf(uhi(p0), s1, a1);  q1 = fmaf(uhi(n0p), s1, q1);
                a2 = fmaf(ulo(p1), s2, a2);  q0 = fmaf(ulo(n1p), s2, q0);
                a3 = fmaf(uhi(p1), s3, a3);  q1 = fmaf(uhi(n1p), s3, q1);
            }
        }
        const float amain = (a0 + a1) + (a2 + a3) + bh;
        const float npart = q0 + q1;
        if (!low) {
            gz[jj]  = amain;
            gnh[jj] = npart;
        }

        asm volatile("s_waitcnt lgkmcnt(0)" ::: "memory");
        __builtin_amdgcn_s_barrier();

        if (low) {
            const float hr = amain;
            const float hz = gz[j];
            const float hn = (npart + bhn) + gnh[j];
            const float r = 1.f / (1.f + __expf(-(xr + hr)));
            const float z = 1.f / (1.f + __expf(-(xz + hz)));
            const float x2 = xn + r * hn;
            const float ax = fabsf(x2);
            const float e  = __expf(-2.f * ax);
            const float nn = copysignf((1.f - e) / (1.f + e), x2);  // tanh
            const float hnew = nn + z * (hj - nn);   // (1-z)*n + z*h
            hj = hnew;
            hs[j] = hnew;
            const int s = dir ? (S_LEN - 1 - t) : t;
            outs[((size_t)s * 64 + b) * 256 + dir * 128 + j] = hnew;
            xr = pxr; xz = pxz; xn = pxn;
        }

        asm volatile("s_waitcnt lgkmcnt(0)" ::: "memory");
        __builtin_amdgcn_s_barrier();
    }

    if (low) hid_out[dir * (64*128) + b * 128 + j] = hj;
}

// ---------------------------------------------------------------------------
// Batch-axis softmax (over b, 64 lanes = one wave) + weighted partial
// reduction over a 32-step s-chunk.  logits are in (S, C, B) layout.
// ---------------------------------------------------------------------------
__global__ __launch_bounds__(256)
void attn_reduce(const float* __restrict__ lt,    // (S,256,64)
                 const float* __restrict__ outs,  // (S,64,256)
                 float* __restrict__ part)        // (64 chunks,64 b,256 c)
{
    __shared__ float ltile[64 * 64];
    __shared__ float otile[64 * 65];

    const int tid  = threadIdx.x;
    const int lane = tid & 63;
    const int wv   = tid >> 6;
    const int c0   = blockIdx.x * 64;
    const int sc   = blockIdx.y;

    float acc[16];
    #pragma unroll
    for (int i = 0; i < 16; ++i) acc[i] = 0.f;

    for (int si = 0; si < 32; ++si) {
        const int s = sc * 32 + si;

        const float4* src = reinterpret_cast<const float4*>(
            lt + (size_t)s * 16384 + (size_t)c0 * 64);
        #pragma unroll
        for (int i = 0; i < 4; ++i)
            reinterpret_cast<float4*>(ltile)[tid + i * 256] = src[tid + i * 256];

        #pragma unroll
        for (int i = 0; i < 4; ++i) {
            int idx = tid + i * 256;
            int bb = idx >> 4, c4 = (idx & 15) * 4;
            float4 v = *reinterpret_cast<const float4*>(
                &outs[((size_t)s * 64 + bb) * 256 + c0 + c4]);
            otile[bb*65 + c4+0] = v.x; otile[bb*65 + c4+1] = v.y;
            otile[bb*65 + c4+2] = v.z; otile[bb*65 + c4+3] = v.w;
        }
        __syncthreads();

        #pragma unroll
        for (int ci = 0; ci < 16; ++ci) {
            int c = wv * 16 + ci;
            float x = ltile[c * 64 + lane];
            float m = x;
            #pragma unroll
            for (int off = 32; off; off >>= 1)
                m = fmaxf(m, __shfl_xor(m, off));
            float e = __expf(x - m);
            float ssum = e;
            #pragma unroll
            for (int off = 32; off; off >>= 1)
                ssum += __shfl_xor(ssum, off);
            float attn = e / ssum;
            acc[ci] += attn * otile[lane * 65 + c];
        }
        __syncthreads();
    }

    #pragma unroll
    for (int ci = 0; ci < 16; ++ci) {
        int c = wv * 16 + ci;
        part[(size_t)sc * 16384 + (size_t)lane * 256 + c0 + c] = acc[ci];
    }
}

__global__ __launch_bounds__(256)
void reduce_part(const float* __restrict__ part, float* __restrict__ sent)
{
    int idx = blockIdx.x * 256 + threadIdx.x;
    float s = 0.f;
    for (int sc = 0; sc < 64; ++sc)
        s += part[(size_t)sc * 16384 + idx];
    sent[idx] = s;
}

// ---------------------------------------------------------------------------
extern "C" void kernel_launch(void* const* d_in, const int* in_sizes, int n_in,
                              void* d_out, int out_size, void* d_ws, size_t ws_size,
                              hipStream_t stream)
{
    const float* inp    = (const float*)d_in[0];
    const float* hid0   = (const float*)d_in[1];
    const float* w_ih_f = (const float*)d_in[2];
    const float* w_hh_f = (const float*)d_in[3];
    const float* b_ih_f = (const float*)d_in[4];
    const float* b_hh_f = (const float*)d_in[5];
    const float* w_ih_b = (const float*)d_in[6];
    const float* w_hh_b = (const float*)d_in[7];
    const float* b_ih_b = (const float*)d_in[8];
    const float* b_hh_b = (const float*)d_in[9];
    const float* attn_w = (const float*)d_in[10];
    const float* attn_b = (const float*)d_in[11];
    const float* comb_w = (const float*)d_in[12];

    float* out = (float*)d_out;   // [0,16384): sent, [16384,32768): hid_out

    char* ws = (char*)d_ws;
    const size_t XG_BYTES = (size_t)S_LEN * BATCH * 384 * 4;  // 201,326,592
    const size_t OS_BYTES = (size_t)S_LEN * BATCH * 256 * 4;  // 134,217,728
    if (ws_size < 2 * XG_BYTES + OS_BYTES) return;

    float* xg_f   = (float*)(ws);
    float* xg_b   = (float*)(ws + XG_BYTES);
    float* outs   = (float*)(ws + 2 * XG_BYTES);
    float* logits = (float*)(ws + XG_BYTES);          // reuse xg_b (dead after gru)
    float* Wc     = (float*)(ws + XG_BYTES + (size_t)160 * 1024 * 1024);  // spare tail
    float* bc     = Wc + 256 * 256;
    float* part   = (float*)(ws);                     // reuse xg_f (dead after gru)

    const int M = S_LEN * BATCH;                // 131072
    dim3 blk(256);

    // K1: input-side gates, both directions (MFMA split-bf16)
    gemm_mfma<0><<<dim3(3, 1024), blk, 0, stream>>>(inp, w_ih_f, b_ih_f, xg_f, M, 384, 256);
    gemm_mfma<0><<<dim3(3, 1024), blk, 0, stream>>>(inp, w_ih_b, b_ih_b, xg_b, M, 384, 256);

    // K2: sequential bidirectional GRU (128 WGs x 256 thr)
    gru_scan<<<dim3(128), dim3(256), 0, stream>>>(
        xg_f, xg_b, w_hh_f, w_hh_b, b_hh_f, b_hh_b, hid0, outs, out + 16384);

    // Kf: Wc = comb_w@attn_w, bc = comb_w@attn_b  (K3/K4 algebraic fusion)
    fuse_wc<<<dim3(257), blk, 0, stream>>>(comb_w, attn_w, attn_b, Wc, bc);

    // K4': logits = outs @ Wc^T + bc, stored transposed (S,C,B) (MFMA)
    gemm_mfma<1><<<dim3(2, 1024), blk, 0, stream>>>(outs, Wc, bc, logits, M, 256, 256);

    // K5: softmax over batch + weighted partial sum over s-chunks
    attn_reduce<<<dim3(4, 64), blk, 0, stream>>>(logits, outs, part);

    // K6: final reduction over s-chunks -> sent
    reduce_part<<<dim3(64), blk, 0, stream>>>(part, out);
}